// Round 2
// baseline (576.227 us; speedup 1.0000x reference)
//
#include <hip/hip_runtime.h>
#include <cstdint>
#include <cstddef>

#define B_  8
#define C_  256
#define HW_ 16384
#define K_  64

// ---------------- K0: zero sums+counts ----------------
__global__ __launch_bounds__(256) void k_zero(float* __restrict__ p, int n) {
    int i = blockIdx.x * 256 + threadIdx.x;
    if (i < n) p[i] = 0.f;
}

// ---------------- K1: segment scatter-sum ----------------
// grid (64, 8): 256 pixels per block, batch b = blockIdx.y
// thread = channel c. LDS accumulator [K][C]; k is block-uniform per pixel,
// so lsum[k*C+c] is touched only by thread c -> race-free, conflict-free.
// no-return atomicAdd -> ds_add_f32 (no dependency chain, throughput-bound).
__global__ __launch_bounds__(256) void k_scatter(const float* __restrict__ x,
                                                 const int* __restrict__ idx,
                                                 float* __restrict__ sums,
                                                 float* __restrict__ counts) {
    __shared__ float lsum[K_ * C_];   // 64 KB
    __shared__ int   sidx[256];
    __shared__ float lcnt[K_];
    const int tid = threadIdx.x;
    const int b = blockIdx.y;
    const int p0 = blockIdx.x * 256;

    float4 z4 = make_float4(0.f, 0.f, 0.f, 0.f);
    for (int i = tid; i < K_ * C_ / 4; i += 256) ((float4*)lsum)[i] = z4;
    if (tid < K_) lcnt[tid] = 0.f;
    sidx[tid] = idx[b * HW_ + p0 + tid];
    __syncthreads();

    atomicAdd(&lcnt[sidx[tid]], 1.f);   // ds_add_f32, no-return

    const int c = tid;
    const float4* xr = (const float4*)(x + ((size_t)b * C_ + c) * HW_ + p0);
    #pragma unroll 4
    for (int p4 = 0; p4 < 64; ++p4) {
        float4 v = xr[p4];
        int k0 = sidx[p4 * 4 + 0];
        int k1 = sidx[p4 * 4 + 1];
        int k2 = sidx[p4 * 4 + 2];
        int k3 = sidx[p4 * 4 + 3];
        atomicAdd(&lsum[k0 * C_ + c], v.x);
        atomicAdd(&lsum[k1 * C_ + c], v.y);
        atomicAdd(&lsum[k2 * C_ + c], v.z);
        atomicAdd(&lsum[k3 * C_ + c], v.w);
    }
    __syncthreads();

    for (int k = 0; k < K_; ++k)
        atomicAdd(&sums[((size_t)b * K_ + k) * C_ + c], lsum[k * C_ + c]);
    if (tid < K_) atomicAdd(&counts[b * K_ + tid], lcnt[tid]);
}

// ---------------- K2: means + M=W·Wt + convw transpose ----------------
__global__ __launch_bounds__(256) void k_prep(const float* __restrict__ sums,
                                              const float* __restrict__ counts,
                                              const float* __restrict__ Wm,
                                              const float* __restrict__ convw,
                                              float* __restrict__ means,
                                              float* __restrict__ Mm,
                                              float* __restrict__ cwT) {
    const int bx = blockIdx.x, t = threadIdx.x;
    __shared__ float wl[C_];
    if (bx < B_ * K_) {
        float cnt = counts[bx];
        float denom = cnt + (cnt == 0.f ? 1.f : 0.f);
        means[(size_t)bx * C_ + t] = sums[(size_t)bx * C_ + t] / denom;
    } else if (bx < B_ * K_ + C_) {
        int cr = bx - B_ * K_;
        wl[t] = Wm[cr * C_ + t];
        __syncthreads();
        float acc = 0.f;
        for (int e = 0; e < C_; ++e) acc += wl[e] * Wm[t * C_ + e];
        Mm[cr * C_ + t] = acc;
    } else {
        int cr = bx - (B_ * K_ + C_);
        cwT[cr * C_ + t] = convw[t * C_ + cr];
    }
}

// ---------------- K3: P[b,i,:] = means[b,i,:] @ M ----------------
__global__ __launch_bounds__(256) void k_P(const float* __restrict__ means,
                                           const float* __restrict__ Mm,
                                           float* __restrict__ P) {
    const int bi = blockIdx.x;
    const int d = threadIdx.x;
    __shared__ float ml[C_];
    ml[d] = means[(size_t)bi * C_ + d];
    __syncthreads();
    float acc = 0.f;
    for (int cc = 0; cc < C_; ++cc) acc += ml[cc] * Mm[cc * C_ + d];
    P[(size_t)bi * C_ + d] = acc;
}

// ---------------- K4: G[b,i,j] = P[b,i,:] . means[b,j,:] ----------------
__global__ __launch_bounds__(256) void k_G(const float* __restrict__ P,
                                           const float* __restrict__ means,
                                           float* __restrict__ G) {
    const int bi = blockIdx.x;
    const int b = bi >> 6;
    const int t = threadIdx.x;
    __shared__ float pl[C_];
    pl[t] = P[(size_t)bi * C_ + t];
    __syncthreads();
    const int j = t >> 2, q = t & 3;
    const float* mj = means + ((size_t)b * K_ + j) * C_ + q * 64;
    const float* pq = pl + q * 64;
    float acc = 0.f;
    for (int d = 0; d < 64; ++d) acc += pq[d] * mj[d];
    acc += __shfl_xor(acc, 1);
    acc += __shfl_xor(acc, 2);
    if (q == 0) G[(size_t)bi * K_ + j] = acc;
}

// ---------------- K5: adj row + agg[b,i,:] = adj[i,:] @ means[b] ----------
__global__ __launch_bounds__(256) void k_agg(const float* __restrict__ G,
                                             const float* __restrict__ means,
                                             float* __restrict__ agg) {
    const int bi = blockIdx.x;
    const int b = bi >> 6, i = bi & 63;
    const int t = threadIdx.x;
    __shared__ float adjl[K_];
    if (t < K_) {
        int j = t;
        float Gii = G[(size_t)bi * K_ + i];
        float Gjj = G[((size_t)b * K_ + j) * K_ + j];
        float Gij = G[(size_t)bi * K_ + j];
        float quad = Gii + Gjj - 2.f * Gij;
        adjl[j] = (j == i) ? 0.f : expf(-quad);
    }
    __syncthreads();
    float acc = 0.f;
    for (int j = 0; j < K_; ++j)
        acc += adjl[j] * means[((size_t)b * K_ + j) * C_ + t];
    agg[(size_t)bi * C_ + t] = acc;
}

// ---------------- K6: proj[b,k,:] = agg[b,k,:] @ convwT ----------------
__global__ __launch_bounds__(256) void k_proj(const float* __restrict__ agg,
                                              const float* __restrict__ cwT,
                                              float* __restrict__ proj) {
    const int bk = blockIdx.x;
    const int o = threadIdx.x;
    __shared__ float al[C_];
    al[o] = agg[(size_t)bk * C_ + o];
    __syncthreads();
    float acc = 0.f;
    for (int cc = 0; cc < C_; ++cc) acc += al[cc] * cwT[cc * C_ + o];
    proj[(size_t)bk * C_ + o] = acc;
}

// ---------------- K7: out = convw (x) x + proj gather ----------------
// grid (2 o-tiles, 128 pixel-tiles, 8 batches): o fastest so the 2 blocks
// sharing an x pixel-tile are L2-adjacent. 128x128x32 tile, 256 thr, 8x8 acc
// with 4+4 split fragments (bank-conflict-free LDS reads).
#define BM 128
#define BN 128
#define BKK 32
__global__ __launch_bounds__(256) void k_gemm(const float* __restrict__ x,
                                              const int* __restrict__ idx,
                                              const float* __restrict__ cwT,
                                              const float* __restrict__ proj,
                                              float* __restrict__ out) {
    __shared__ float As[BKK][BM];   // As[k][m] = convw[o0+m][kt+k]
    __shared__ float Bs[BKK][BN];   // Bs[k][n] = x[b][kt+k][p0+n]
    const int tid = threadIdx.x;
    const int o0 = blockIdx.x * BM;
    const int p0 = blockIdx.y * BN;
    const int b = blockIdx.z;

    float acc[8][8];
    #pragma unroll
    for (int i = 0; i < 8; ++i)
        #pragma unroll
        for (int j = 0; j < 8; ++j) acc[i][j] = 0.f;

    const float4* cwT4 = (const float4*)cwT;
    const float4* x4 = (const float4*)(x + (size_t)b * C_ * HW_);

    const int tm4 = (tid & 15) * 4;   // rows tm4..+3 and 64+tm4..+3
    const int tn4 = (tid >> 4) * 4;   // cols tn4..+3 and 64+tn4..+3

    for (int kt = 0; kt < C_; kt += BKK) {
        #pragma unroll
        for (int it = 0; it < 4; ++it) {
            int li = tid + it * 256;          // float4 index, 0..1023
            int row = li >> 5, col4 = li & 31;
            ((float4*)As)[li] = cwT4[(size_t)(kt + row) * (C_ / 4) + o0 / 4 + col4];
            ((float4*)Bs)[li] = x4[(size_t)(kt + row) * (HW_ / 4) + p0 / 4 + col4];
        }
        __syncthreads();
        #pragma unroll
        for (int kk = 0; kk < BKK; ++kk) {
            float4 a0 = *(const float4*)&As[kk][tm4];
            float4 a1 = *(const float4*)&As[kk][tm4 + 64];
            float4 b0 = *(const float4*)&Bs[kk][tn4];
            float4 b1 = *(const float4*)&Bs[kk][tn4 + 64];
            float av[8] = {a0.x, a0.y, a0.z, a0.w, a1.x, a1.y, a1.z, a1.w};
            float bv[8] = {b0.x, b0.y, b0.z, b0.w, b1.x, b1.y, b1.z, b1.w};
            #pragma unroll
            for (int i = 0; i < 8; ++i)
                #pragma unroll
                for (int j = 0; j < 8; ++j)
                    acc[i][j] += av[i] * bv[j];
        }
        __syncthreads();
    }

    // epilogue: rows o0 + {tm4..tm4+3, 64+tm4..}, cols p0 + {tn4.., 64+tn4..}
    int kp[8];
    #pragma unroll
    for (int j = 0; j < 8; ++j) {
        int col = (j < 4) ? (tn4 + j) : (64 + tn4 + j - 4);
        kp[j] = idx[b * HW_ + p0 + col];
    }
    #pragma unroll
    for (int i = 0; i < 8; ++i) {
        const int o = o0 + ((i < 4) ? (tm4 + i) : (64 + tm4 + i - 4));
        float r[8];
        #pragma unroll
        for (int j = 0; j < 8; ++j)
            r[j] = acc[i][j] + proj[((size_t)b * K_ + kp[j]) * C_ + o];
        float* orow = out + ((size_t)b * C_ + o) * HW_ + p0;
        *(float4*)(orow + tn4)      = make_float4(r[0], r[1], r[2], r[3]);
        *(float4*)(orow + 64 + tn4) = make_float4(r[4], r[5], r[6], r[7]);
    }
}

// ---------------- host ----------------
extern "C" void kernel_launch(void* const* d_in, const int* in_sizes, int n_in,
                              void* d_out, int out_size, void* d_ws, size_t ws_size,
                              hipStream_t stream) {
    const float* x     = (const float*)d_in[0];
    const int*   idx   = (const int*)d_in[1];
    const float* Wm    = (const float*)d_in[2];
    const float* convw = (const float*)d_in[3];
    float* out = (float*)d_out;
    float* wsf = (float*)d_ws;

    const size_t N_SUMS = (size_t)B_ * K_ * C_;  // 131072
    const size_t N_CNT  = (size_t)B_ * K_;       // 512
    const size_t N_M    = (size_t)C_ * C_;       // 65536
    const size_t N_G    = (size_t)B_ * K_ * K_;  // 32768

    // proj + cwT always live in ws (needed during final kernel): 768 KB
    float* proj = wsf;
    float* cwT  = wsf + N_SUMS;

    // early intermediates: ws if it fits, else a d_out tail region that is
    // fully consumed (by k_proj) before k_gemm overwrites d_out.
    const size_t earlyN = N_SUMS + N_CNT + N_SUMS + N_M + N_SUMS + N_G + N_SUMS;
    const size_t needAll = (N_SUMS + N_M + earlyN) * sizeof(float);
    float* early = (ws_size >= needAll) ? (wsf + N_SUMS + N_M)
                                        : (out + (size_t)16 * 1024 * 1024);

    float* sums   = early;
    float* counts = sums + N_SUMS;
    float* means  = counts + N_CNT;
    float* Mm     = means + N_SUMS;
    float* P      = Mm + N_M;
    float* G      = P + N_SUMS;
    float* agg    = G + N_G;

    k_zero<<<dim3(514), dim3(256), 0, stream>>>(sums, (int)(N_SUMS + N_CNT));
    k_scatter<<<dim3(64, 8), dim3(256), 0, stream>>>(x, idx, sums, counts);
    k_prep<<<dim3(512 + 256 + 256), dim3(256), 0, stream>>>(sums, counts, Wm, convw,
                                                            means, Mm, cwT);
    k_P<<<dim3(512), dim3(256), 0, stream>>>(means, Mm, P);
    k_G<<<dim3(512), dim3(256), 0, stream>>>(P, means, G);
    k_agg<<<dim3(512), dim3(256), 0, stream>>>(G, means, agg);
    k_proj<<<dim3(512), dim3(256), 0, stream>>>(agg, cwT, proj);
    k_gemm<<<dim3(2, HW_ / BN, B_), dim3(256), 0, stream>>>(x, idx, cwT, proj, out);
}

// Round 4
// 522.670 us; speedup vs baseline: 1.1025x; 1.1025x over previous
//
#include <hip/hip_runtime.h>
#include <cstdint>
#include <cstddef>

#define B_  8
#define C_  256
#define HW_ 16384
#define K_  64

typedef __attribute__((ext_vector_type(8))) short bf16x8;
typedef __attribute__((ext_vector_type(4))) float f32x4;

__device__ __forceinline__ unsigned f2bf(float f) {
    unsigned u = __builtin_bit_cast(unsigned, f);
    return (u + 0x7FFFu + ((u >> 16) & 1u)) >> 16;
}
__device__ __forceinline__ float bf2f(unsigned h) {
    unsigned u = h << 16;
    return __builtin_bit_cast(float, u);
}

// ---------------- K1: segment scatter-sum -> per-block partials ----------
// grid (64, 8): 256 pixels per block. thread = channel c. LDS acc [K][C];
// k is block-uniform per pixel -> thread c owns column c. Flush = coalesced
// streaming stores of partials (NO global atomics).
__global__ __launch_bounds__(256) void k_scatter(const float* __restrict__ x,
                                                 const int* __restrict__ idx,
                                                 float* __restrict__ part,
                                                 float* __restrict__ pcnt) {
    __shared__ float lsum[K_ * C_];   // 64 KB
    __shared__ int   sidx[256];
    __shared__ float lcnt[K_];
    const int tid = threadIdx.x;
    const int b = blockIdx.y;
    const int pb = blockIdx.x;
    const int p0 = pb * 256;

    float4 z4 = make_float4(0.f, 0.f, 0.f, 0.f);
    for (int i = tid; i < K_ * C_ / 4; i += 256) ((float4*)lsum)[i] = z4;
    if (tid < K_) lcnt[tid] = 0.f;
    sidx[tid] = idx[b * HW_ + p0 + tid];
    __syncthreads();

    atomicAdd(&lcnt[sidx[tid]], 1.f);   // ds_add_f32, no-return

    const int c = tid;
    const float4* xr = (const float4*)(x + ((size_t)b * C_ + c) * HW_ + p0);
    #pragma unroll 4
    for (int p4 = 0; p4 < 64; ++p4) {
        float4 v = xr[p4];
        int k0 = sidx[p4 * 4 + 0];
        int k1 = sidx[p4 * 4 + 1];
        int k2 = sidx[p4 * 4 + 2];
        int k3 = sidx[p4 * 4 + 3];
        atomicAdd(&lsum[k0 * C_ + c], v.x);
        atomicAdd(&lsum[k1 * C_ + c], v.y);
        atomicAdd(&lsum[k2 * C_ + c], v.z);
        atomicAdd(&lsum[k3 * C_ + c], v.w);
    }
    __syncthreads();

    const size_t pbg = (size_t)b * 64 + pb;
    float* dst = part + (pbg * K_) * C_;
    for (int k = 0; k < K_; ++k)
        dst[k * C_ + c] = lsum[k * C_ + c];
    if (tid < K_) pcnt[pbg * K_ + tid] = lcnt[tid];
}

// ---------------- K1b: reduce partials -> means ----------------
__global__ __launch_bounds__(256) void k_reduce(const float* __restrict__ part,
                                                const float* __restrict__ pcnt,
                                                float* __restrict__ means) {
    const int bk = blockIdx.x;
    const int b = bk >> 6, k = bk & 63;
    const int c = threadIdx.x;
    __shared__ float cnt_s;

    if (c < 64) {
        float cl = pcnt[((size_t)b * 64 + c) * K_ + k];
        #pragma unroll
        for (int off = 32; off; off >>= 1) cl += __shfl_down(cl, off);
        if (c == 0) cnt_s = cl;
    }
    __syncthreads();
    const float cnt = cnt_s;
    const float denom = cnt + (cnt == 0.f ? 1.f : 0.f);

    float acc = 0.f;
    #pragma unroll 4
    for (int pb = 0; pb < 64; ++pb)
        acc += part[(((size_t)b * 64 + pb) * K_ + k) * C_ + c];
    means[(size_t)bk * C_ + c] = acc / denom;
}

// ---------------- K2: M=W·Wt + convw transpose ----------------
__global__ __launch_bounds__(256) void k_prep(const float* __restrict__ Wm,
                                              const float* __restrict__ convw,
                                              float* __restrict__ Mm,
                                              float* __restrict__ cwT) {
    const int bx = blockIdx.x, t = threadIdx.x;
    __shared__ float wl[C_];
    if (bx < C_) {
        int cr = bx;
        wl[t] = Wm[cr * C_ + t];
        __syncthreads();
        float acc = 0.f;
        for (int e = 0; e < C_; ++e) acc += wl[e] * Wm[t * C_ + e];
        Mm[cr * C_ + t] = acc;
    } else {
        int cr = bx - C_;
        cwT[cr * C_ + t] = convw[t * C_ + cr];
    }
}

// ---------------- K3: P[b,i,:] = means[b,i,:] @ M ----------------
__global__ __launch_bounds__(256) void k_P(const float* __restrict__ means,
                                           const float* __restrict__ Mm,
                                           float* __restrict__ P) {
    const int bi = blockIdx.x;
    const int d = threadIdx.x;
    __shared__ float ml[C_];
    ml[d] = means[(size_t)bi * C_ + d];
    __syncthreads();
    float acc = 0.f;
    for (int cc = 0; cc < C_; ++cc) acc += ml[cc] * Mm[cc * C_ + d];
    P[(size_t)bi * C_ + d] = acc;
}

// ---------------- K4: quad[b,i,j] = (P_i-P_j).(m_i-m_j) ----------------
// Difference form: exact for symmetric M, avoids Gii+Gjj-2Gij cancellation.
__global__ __launch_bounds__(256) void k_G(const float* __restrict__ P,
                                           const float* __restrict__ means,
                                           float* __restrict__ G) {
    const int bi = blockIdx.x;
    const int b = bi >> 6;
    const int t = threadIdx.x;
    __shared__ float pl[C_], ml[C_];
    pl[t] = P[(size_t)bi * C_ + t];
    ml[t] = means[(size_t)bi * C_ + t];
    __syncthreads();
    const int j = t >> 2, q = t & 3;
    const float* Pj = P + ((size_t)b * K_ + j) * C_ + q * 64;
    const float* mj = means + ((size_t)b * K_ + j) * C_ + q * 64;
    const float* pq = pl + q * 64;
    const float* mq = ml + q * 64;
    float acc = 0.f;
    for (int d0 = 0; d0 < 64; ++d0) {
        int d = (d0 + q * 16) & 63;
        acc += (pq[d] - Pj[d]) * (mq[d] - mj[d]);
    }
    acc += __shfl_xor(acc, 1);
    acc += __shfl_xor(acc, 2);
    if (q == 0) G[(size_t)bi * K_ + j] = acc;
}

// ---------------- K5: adj row + agg[b,i,:] = adj[i,:] @ means[b] ----------
__global__ __launch_bounds__(256) void k_agg(const float* __restrict__ G,
                                             const float* __restrict__ means,
                                             float* __restrict__ agg) {
    const int bi = blockIdx.x;
    const int b = bi >> 6, i = bi & 63;
    const int t = threadIdx.x;
    __shared__ float adjl[K_];
    if (t < K_) {
        int j = t;
        float quad = G[(size_t)bi * K_ + j];
        adjl[j] = (j == i) ? 0.f : expf(-quad);
    }
    __syncthreads();
    float acc = 0.f;
    for (int j = 0; j < K_; ++j)
        acc += adjl[j] * means[((size_t)b * K_ + j) * C_ + t];
    agg[(size_t)bi * C_ + t] = acc;
}

// ---------------- K6: proj[b,k,:] = agg[b,k,:] @ convwT ----------------
__global__ __launch_bounds__(256) void k_proj(const float* __restrict__ agg,
                                              const float* __restrict__ cwT,
                                              float* __restrict__ proj) {
    const int bk = blockIdx.x;
    const int o = threadIdx.x;
    __shared__ float al[C_];
    al[o] = agg[(size_t)bk * C_ + o];
    __syncthreads();
    float acc = 0.f;
    for (int cc = 0; cc < C_; ++cc) acc += al[cc] * cwT[cc * C_ + o];
    proj[(size_t)bk * C_ + o] = acc;
}

// ---------------- K7: out = convw (x) x + proj gather  [bf16-split MFMA] --
// 128x128x32 tile, 4 waves in 2x2, each wave 64x64 via 4x4 16x16x32 MFMAs.
// D = AhiBhi + AhiBlo + AloBhi accumulated in f32.
// Fragment k-mapping: k = 8*(lane>>4)+elem used consistently for A and B
// (correct for any HW (lane-group,elem)->k bijection shared by A and B).
#define BM 128
#define BN 128
#define BKK 32
#define STRD 80   // bytes/row of bf16 tiles (40 bf16, 32 used): even bank coverage

__global__ __launch_bounds__(256) void k_gemm(const float* __restrict__ x,
                                              const int* __restrict__ idx,
                                              const float* __restrict__ convw,
                                              const float* __restrict__ proj,
                                              float* __restrict__ out) {
    __shared__ float Xf[BKK][BN];                       // 16 KB f32 bounce
    __shared__ __align__(16) unsigned char AsH[BM * STRD];  // 10 KB each
    __shared__ __align__(16) unsigned char AsL[BM * STRD];
    __shared__ __align__(16) unsigned char BsH[BN * STRD];
    __shared__ __align__(16) unsigned char BsL[BN * STRD];

    const int tid = threadIdx.x;
    const int o0 = blockIdx.x * BM;
    const int p0 = blockIdx.y * BN;
    const int b  = blockIdx.z;

    const int lane = tid & 63;
    const int wv = tid >> 6;
    const int wo = (wv >> 1) * 64, wp = (wv & 1) * 64;
    const int lr = lane & 15, lg = lane >> 4;

    f32x4 acc[4][4];
    #pragma unroll
    for (int i = 0; i < 4; ++i)
        #pragma unroll
        for (int j = 0; j < 4; ++j) acc[i][j] = (f32x4){0.f, 0.f, 0.f, 0.f};

    const float4* w4 = (const float4*)convw;                       // [256][64]
    const float4* x4 = (const float4*)(x + (size_t)b * C_ * HW_);  // [256][4096]

    for (int kt = 0; kt < C_; kt += BKK) {
        // ---- stage: A-tile (convw[o0..+128][kt..+32]) f32->hi/lo bf16;
        //             X-tile (x[kt..+32][p0..+128]) f32 into Xf.
        #pragma unroll
        for (int it = 0; it < 4; ++it) {
            int li = tid + it * 256;          // 0..1023
            {   // A: 128 rows x 8 float4
                int row = li >> 3, c4 = li & 7;
                float4 v = w4[(size_t)(o0 + row) * (C_ / 4) + (kt >> 2) + c4];
                unsigned h0 = f2bf(v.x), h1 = f2bf(v.y), h2 = f2bf(v.z), h3 = f2bf(v.w);
                unsigned l0 = f2bf(v.x - bf2f(h0)), l1 = f2bf(v.y - bf2f(h1));
                unsigned l2 = f2bf(v.z - bf2f(h2)), l3 = f2bf(v.w - bf2f(h3));
                uint2 hv, lv;
                hv.x = h0 | (h1 << 16); hv.y = h2 | (h3 << 16);
                lv.x = l0 | (l1 << 16); lv.y = l2 | (l3 << 16);
                *(uint2*)&AsH[row * STRD + c4 * 8] = hv;
                *(uint2*)&AsL[row * STRD + c4 * 8] = lv;
            }
            {   // X: 32 rows x 32 float4
                int row = li >> 5, c4 = li & 31;
                *(float4*)&Xf[row][c4 * 4] =
                    x4[(size_t)(kt + row) * (HW_ / 4) + (p0 >> 2) + c4];
            }
        }
        __syncthreads();
        // ---- transpose+split: BsT[p][c] hi/lo from Xf columns
        #pragma unroll
        for (int it = 0; it < 2; ++it) {
            int id = tid + it * 256;          // 0..511
            int p = id & 127, cg = id >> 7;   // c = cg*8 + j
            unsigned hh[8], ll[8];
            #pragma unroll
            for (int j = 0; j < 8; ++j) {
                float v = Xf[cg * 8 + j][p];
                unsigned h = f2bf(v);
                hh[j] = h;
                ll[j] = f2bf(v - bf2f(h));
            }
            uint4 hv, lv;
            hv.x = hh[0] | (hh[1] << 16); hv.y = hh[2] | (hh[3] << 16);
            hv.z = hh[4] | (hh[5] << 16); hv.w = hh[6] | (hh[7] << 16);
            lv.x = ll[0] | (ll[1] << 16); lv.y = ll[2] | (ll[3] << 16);
            lv.z = ll[4] | (ll[5] << 16); lv.w = ll[6] | (ll[7] << 16);
            *(uint4*)&BsH[p * STRD + cg * 16] = hv;
            *(uint4*)&BsL[p * STRD + cg * 16] = lv;
        }
        __syncthreads();
        // ---- compute: 16 b128 frag reads + 48 MFMA per wave
        bf16x8 ah[4], al[4];
        #pragma unroll
        for (int mt = 0; mt < 4; ++mt) {
            int off = (wo + mt * 16 + lr) * STRD + lg * 16;
            ah[mt] = *(const bf16x8*)&AsH[off];
            al[mt] = *(const bf16x8*)&AsL[off];
        }
        #pragma unroll
        for (int nt = 0; nt < 4; ++nt) {
            int off = (wp + nt * 16 + lr) * STRD + lg * 16;
            bf16x8 bh = *(const bf16x8*)&BsH[off];
            bf16x8 bl = *(const bf16x8*)&BsL[off];
            #pragma unroll
            for (int mt = 0; mt < 4; ++mt) {
                acc[mt][nt] = __builtin_amdgcn_mfma_f32_16x16x32_bf16(ah[mt], bh, acc[mt][nt], 0, 0, 0);
                acc[mt][nt] = __builtin_amdgcn_mfma_f32_16x16x32_bf16(ah[mt], bl, acc[mt][nt], 0, 0, 0);
                acc[mt][nt] = __builtin_amdgcn_mfma_f32_16x16x32_bf16(al[mt], bh, acc[mt][nt], 0, 0, 0);
            }
        }
        __syncthreads();
    }

    // ---- epilogue: D[o][p] += proj[b][idx[p]][o]
    #pragma unroll
    for (int nt = 0; nt < 4; ++nt) {
        const int p = p0 + wp + nt * 16 + lr;
        const int kp = idx[b * HW_ + p];
        const float* pr = proj + ((size_t)b * K_ + kp) * C_;
        #pragma unroll
        for (int mt = 0; mt < 4; ++mt) {
            const int ob = o0 + wo + mt * 16 + lg * 4;
            #pragma unroll
            for (int r = 0; r < 4; ++r) {
                const int o = ob + r;
                out[((size_t)b * C_ + o) * HW_ + p] = acc[mt][nt][r] + pr[o];
            }
        }
    }
}

// ---------------- host ----------------
extern "C" void kernel_launch(void* const* d_in, const int* in_sizes, int n_in,
                              void* d_out, int out_size, void* d_ws, size_t ws_size,
                              hipStream_t stream) {
    const float* x     = (const float*)d_in[0];
    const int*   idx   = (const int*)d_in[1];
    const float* Wm    = (const float*)d_in[2];
    const float* convw = (const float*)d_in[3];
    float* out = (float*)d_out;
    float* wsf = (float*)d_ws;

    const size_t N_PART = (size_t)B_ * 64 * K_ * C_;  // 8388608 (33.5 MB)
    const size_t N_PCNT = (size_t)B_ * 64 * K_;       // 32768
    const size_t N_MEAN = (size_t)B_ * K_ * C_;       // 131072
    const size_t N_M    = (size_t)C_ * C_;            // 65536
    const size_t N_G    = (size_t)B_ * K_ * K_;       // 32768
    const size_t outN   = (size_t)B_ * C_ * HW_;      // 33554432

    // proj + cwT must survive into k_gemm/k_proj -> always in ws (768 KB)
    float* proj = wsf;
    float* cwT  = wsf + N_MEAN;

    // early intermediates: ws if it fits, else exact-fit tail of d_out
    // (fully consumed by k_proj before k_gemm writes out).
    const size_t earlyN = N_PART + N_PCNT + N_MEAN + N_M + N_MEAN + N_G + N_MEAN;
    const size_t needAll = (N_MEAN + N_M + earlyN) * sizeof(float);
    float* early = (ws_size >= needAll) ? (wsf + N_MEAN + N_M)
                                        : (out + (outN - earlyN));

    float* part  = early;
    float* pcnt  = part + N_PART;
    float* means = pcnt + N_PCNT;
    float* Mm    = means + N_MEAN;
    float* P     = Mm + N_M;
    float* G     = P + N_MEAN;
    float* agg   = G + N_G;

    k_scatter<<<dim3(64, 8), dim3(256), 0, stream>>>(x, idx, part, pcnt);
    k_reduce<<<dim3(512), dim3(256), 0, stream>>>(part, pcnt, means);
    k_prep<<<dim3(512), dim3(256), 0, stream>>>(Wm, convw, Mm, cwT);
    k_P<<<dim3(512), dim3(256), 0, stream>>>(means, Mm, P);
    k_G<<<dim3(512), dim3(256), 0, stream>>>(P, means, G);
    k_agg<<<dim3(512), dim3(256), 0, stream>>>(G, means, agg);
    k_proj<<<dim3(512), dim3(256), 0, stream>>>(agg, cwT, proj);
    k_gemm<<<dim3(2, HW_ / BN, B_), dim3(256), 0, stream>>>(x, idx, convw, proj, out);
}